// Round 17
// baseline (433.382 us; speedup 1.0000x reference)
//
#include <hip/hip_runtime.h>
#include <math.h>

#define SEQL   4096
#define DMODEL 1024
#define NH     16
#define DHEAD  64
#define SPOKES 3072
#define NQUERY (SEQL - SPOKES)     // 1024
#define QKVN   (3 * DMODEL)        // 3072
#define LOG2E  1.4426950408889634f

typedef short bf16x8 __attribute__((ext_vector_type(8)));
typedef short bf16x4 __attribute__((ext_vector_type(4)));
typedef float f32x4  __attribute__((ext_vector_type(4)));

__device__ __forceinline__ short f2bf(float f) {
    unsigned u = __builtin_bit_cast(unsigned, f);
    u += 0x7fffu + ((u >> 16) & 1u);     // RNE
    return (short)(u >> 16);
}
__device__ __forceinline__ float bf2f(short s) {
    unsigned u = ((unsigned)(unsigned short)s) << 16;
    return __builtin_bit_cast(float, u);
}
// packed f32x2 -> bf16x2 (RNE), low half = lo
__device__ __forceinline__ unsigned cvt_pk_bf16(float lo, float hi) {
    unsigned u;
    asm("v_cvt_pk_bf16_f32 %0, %1, %2" : "=v"(u) : "v"(lo), "v"(hi));
    return u;
}
// raw 2^x (v_exp_f32); input here is always <= 0 or -inf
__device__ __forceinline__ float fast_exp2(float x) {
#if __has_builtin(__builtin_amdgcn_exp2f)
    return __builtin_amdgcn_exp2f(x);
#else
    float r; asm("v_exp_f32 %0, %1" : "=v"(r) : "v"(x)); return r;
#endif
}
// XOR swizzle on byte bits 4..6, keyed by LDS row (rows are 128B).
__device__ __forceinline__ int swz(int row) { return ((row & 7) ^ (row >> 3)) << 4; }

// async global->LDS, 16B per lane; LDS dest = wave-uniform base + lane*16
__device__ __forceinline__ void gload_lds16(const void* g, void* l) {
    __builtin_amdgcn_global_load_lds(
        (const __attribute__((address_space(1))) unsigned int*)g,
        (__attribute__((address_space(3))) unsigned int*)l,
        16, 0, 0);
}

// ---------------------------------------------------------------------------
// Merged f32 -> bf16 conversion for x, qkv_w, out_w (one launch)
// ---------------------------------------------------------------------------
#define CVT_N0 (SEQL * DMODEL / 8)     // 524288
#define CVT_N1 (QKVN * DMODEL / 8)     // 393216
#define CVT_N2 (DMODEL * DMODEL / 8)   // 131072
__global__ __launch_bounds__(256) void cvt_all(
    const float* __restrict__ x, const float* __restrict__ wq, const float* __restrict__ wo,
    short* __restrict__ xb, short* __restrict__ wqb, short* __restrict__ wob)
{
    int i = blockIdx.x * 256 + threadIdx.x;       // [0, CVT_N0+CVT_N1+CVT_N2)
    const float* src; short* dst;
    if (i < CVT_N0)               { src = x;  dst = xb; }
    else if (i < CVT_N0 + CVT_N1) { src = wq; dst = wqb; i -= CVT_N0; }
    else                          { src = wo; dst = wob; i -= CVT_N0 + CVT_N1; }
    float4 a = ((const float4*)src)[i * 2];
    float4 b = ((const float4*)src)[i * 2 + 1];
    bf16x8 v;
    v[0] = f2bf(a.x); v[1] = f2bf(a.y); v[2] = f2bf(a.z); v[3] = f2bf(a.w);
    v[4] = f2bf(b.x); v[5] = f2bf(b.y); v[6] = f2bf(b.z); v[7] = f2bf(b.w);
    ((bf16x8*)dst)[i] = v;
}

// ---------------------------------------------------------------------------
// bf16 MFMA GEMM: C = A * B^T, 128x128 tile, BK=64 (plain blockIdx mapping;
// the r16 XCD swizzle was null-to-negative -> reverted).
// FUSE (gemm1 only): apply cos-scale + axial RoPE (+ log2e on q) in the
// epilogue for q/k column tiles. A 128-col tile = 2 complete heads; the RoPE
// pair (d, d+32) is j<->j+2 (thread-local); the row-norm is 4 local squares
// + shfl_xor over the c bits (rows are c-invariant in this fragment layout).
// ---------------------------------------------------------------------------
template<bool BF16OUT, bool FUSE>
__global__ __launch_bounds__(256) void gemm_bf16(
    const short* __restrict__ A, const short* __restrict__ B, void* __restrict__ Cv,
    int K, int ldc,
    const float* __restrict__ pos, const float* __restrict__ scale,
    const float* __restrict__ freqs)
{
    __shared__ short As[128 * 64];
    __shared__ short Bs[128 * 64];

    const int t = threadIdx.x;
    const int lane = t & 63, w = t >> 6;
    const int c = lane & 15, g = lane >> 4;
    const int wr = w >> 1, wc = w & 1;
    const int m0 = blockIdx.y * 128, n0 = blockIdx.x * 128;

    f32x4 acc[4][4] = {};

    for (int k0 = 0; k0 < K; k0 += 64) {
        __syncthreads();
        #pragma unroll
        for (int i = 0; i < 4; ++i) {
            const int chunk = (w * 4 + i) * 64 + lane;
            const int row = chunk >> 3, cc = chunk & 7;
            gload_lds16(A + (size_t)(m0 + row) * K + k0 + cc * 8,
                        As + (size_t)(w * 4 + i) * 512);
            gload_lds16(B + (size_t)(n0 + row) * K + k0 + cc * 8,
                        Bs + (size_t)(w * 4 + i) * 512);
        }
        __syncthreads();

        #pragma unroll
        for (int kk = 0; kk < 2; ++kk) {
            bf16x8 af[4], bf[4];
            #pragma unroll
            for (int i = 0; i < 4; ++i)
                af[i] = *(const bf16x8*)(As + (wr * 64 + i * 16 + c) * 64 + kk * 32 + g * 8);
            #pragma unroll
            for (int j = 0; j < 4; ++j)
                bf[j] = *(const bf16x8*)(Bs + (wc * 64 + j * 16 + c) * 64 + kk * 32 + g * 8);
            #pragma unroll
            for (int i = 0; i < 4; ++i)
                #pragma unroll
                for (int j = 0; j < 4; ++j)
                    acc[i][j] = __builtin_amdgcn_mfma_f32_16x16x32_bf16(af[i], bf[j], acc[i][j], 0, 0, 0);
        }
    }

    if (FUSE && n0 < 2048) {               // q or k column tile (block-uniform)
        const bool isq = (n0 < 1024);
        const int h = ((n0 >> 6) + wc) & 15;         // this wave-half's head
        const float ss = sqrtf(fabsf(scale[h]) + 1e-8f);
        const float fA = freqs[256 + h * 16 + c];    // dim c      (theta from pos_y)
        const float fB = freqs[h * 16 + c];          // dim 16+c   (theta from pos_x)
        #pragma unroll
        for (int i = 0; i < 4; ++i)
            #pragma unroll
            for (int r = 0; r < 4; ++r) {
                const int row = m0 + wr * 64 + i * 16 + g * 4 + r;
                float a0 = acc[i][0][r], a1 = acc[i][1][r];
                float a2 = acc[i][2][r], a3 = acc[i][3][r];
                float sq = a0 * a0 + a1 * a1 + a2 * a2 + a3 * a3;
                sq += __shfl_xor(sq, 1);
                sq += __shfl_xor(sq, 2);
                sq += __shfl_xor(sq, 4);
                sq += __shfl_xor(sq, 8);             // sum over the 16 c-lanes
                const float f = ss * rsqrtf(sq + 1e-8f);
                a0 *= f; a1 *= f; a2 *= f; a3 *= f;
                const float px = pos[row * 2 + 0];
                const float py = pos[row * 2 + 1];
                const float thA = (py * 2.0f - 1.0f) * fA;
                const float thB = (px * 2.0f - 1.0f) * fB;
                const float cA = cosf(thA), sA = sinf(thA);
                const float cB = cosf(thB), sB = sinf(thB);
                float n0v = a0 * cA - a2 * sA;       // dim c
                float n2v = a2 * cA + a0 * sA;       // dim 32+c
                float n1v = a1 * cB - a3 * sB;       // dim 16+c
                float n3v = a3 * cB + a1 * sB;       // dim 48+c
                if (isq) { n0v *= LOG2E; n1v *= LOG2E; n2v *= LOG2E; n3v *= LOG2E; }
                acc[i][0][r] = n0v; acc[i][1][r] = n1v;
                acc[i][2][r] = n2v; acc[i][3][r] = n3v;
            }
    }

    #pragma unroll
    for (int i = 0; i < 4; ++i)
        #pragma unroll
        for (int r = 0; r < 4; ++r) {
            const int row = m0 + wr * 64 + i * 16 + g * 4 + r;
            #pragma unroll
            for (int j = 0; j < 4; ++j) {
                const int col = n0 + wc * 64 + j * 16 + c;
                const float v = acc[i][j][r];
                if (BF16OUT) ((short*)Cv)[(size_t)row * ldc + col] = f2bf(v);
                else         ((float*)Cv)[(size_t)row * ldc + col] = v;
            }
        }
}

// ---------------------------------------------------------------------------
// Fused flash attention (r13 configuration — best measured, 182.9 us total):
// 4 waves x 16 q rows = 64 q rows / block, KVBLK=64, single-buffered K/V
// (24 KB LDS), two barriers per tile, fixed-max softmax, deferred l reduce.
// grid = (144, 16).
// ---------------------------------------------------------------------------
__global__ __launch_bounds__(256) void attn_fused(
    const short* __restrict__ qkv, const float* __restrict__ scale,
    short* __restrict__ attn,
    short* __restrict__ pacc_c, float* __restrict__ pml_c, float* __restrict__ pml0_c,
    short* __restrict__ pacc_q, float* __restrict__ pml_q, float* __restrict__ pml0_q)
{
    __shared__ short Kl[64 * 64];          // 8 KB
    __shared__ short VTl[64 * 64];         // 8 KB
    __shared__ short Pl[4][16 * 64];       // 8 KB

    const int h = blockIdx.y;
    const int t = threadIdx.x, lane = t & 63, w = t >> 6;
    const int c = lane & 15, g = lane >> 4;
    const int qcol = h * DHEAD, kcol = DMODEL + h * DHEAD, vcol = 2 * DMODEL + h * DHEAD;

    // ---- decode chunk ----
    const int xc = blockIdx.x;
    bool causal; int z, NS, q0, kt0, ktn, qt = 0, qb = 0;
    if (xc < 48) {
        causal = false; qb = xc / 3; z = xc - qb * 3; NS = 3;
        q0 = SPOKES + qb * 64; kt0 = z * 16; ktn = 16;
    } else {
        causal = true;
        if (xc < 96)       { const int i = xc - 48; qt = 47 - i / 3; z = i - (i / 3) * 3; NS = 3; }
        else if (xc < 128) { const int i = xc - 96; qt = 31 - (i >> 1); z = i & 1; NS = 2; }
        else               { qt = 143 - xc; z = 0; NS = 1; }
        q0 = qt * 64;
        const int full = qt + 1, b = full / NS, r = full - b * NS;
        kt0 = z * b + (z < r ? z : r);
        ktn = b + (z < r ? 1 : 0);
    }

    const int qg = q0 + w * 16 + c;       // this lane's q row

    // fixed softmax max in log2 domain
    const float Mlog = (fabsf(scale[h]) * 1.02f + 0.5f) * LOG2E;
    const f32x4 negM4 = {-Mlog, -Mlog, -Mlog, -Mlog};

    bf16x8 qf0, qf1;
    {
        const short* qrow = qkv + (size_t)qg * QKVN + qcol;
        qf0 = *(const bf16x8*)(qrow + g * 8);
        qf1 = *(const bf16x8*)(qrow + 32 + g * 8);
    }

    float l = 0.0f;                        // per-lane partial (reduced in epilogue)
    f32x4 acc[4] = {};
    bf16x8 vregA, vregB;

    // ---- staging helpers (single buffer) ----
    auto KDMA = [&](int kt) {
        const int k0 = kt * 64;
        #pragma unroll
        for (int i = 0; i < 2; ++i) {
            const int ch = i * 256 + t;                 // 16B chunk index
            const int kv = ch >> 3, s = ch & 7;
            const int o = s ^ ((kv & 7) ^ (kv >> 3));   // pre-swizzled source octet
            gload_lds16(qkv + (size_t)(k0 + kv) * QKVN + kcol + o * 8,
                        (char*)Kl + i * 4096 + w * 1024);
        }
    };
    auto VLOAD = [&](int kt) {
        const int k0 = kt * 64;
        const short* v0 = qkv + (size_t)(k0 + 2 * (t >> 3)) * QKVN + vcol + (t & 3) * 8;
        // thread t owns kv pair {2*(t>>3), 2*(t>>3)+1} x d-octet (t&7)
        const short* vv = qkv + (size_t)(k0 + 2 * (t >> 3)) * QKVN + vcol + (t & 7) * 8;
        vregA = *(const bf16x8*)vv;
        vregB = *(const bf16x8*)(vv + QKVN);
        (void)v0;
    };
    auto VWRITE = [&]() {
        const int p2 = t >> 3, oc = t & 7;
        #pragma unroll
        for (int j = 0; j < 8; ++j) {
            const int d = oc * 8 + j;
            const unsigned u = ((unsigned)(unsigned short)vregA[j]) |
                               (((unsigned)(unsigned short)vregB[j]) << 16);
            *(unsigned*)((char*)VTl + d * 128 + ((4 * p2) ^ swz(d))) = u;
        }
    };

    // ---- prologue: stage tile kt0 ----
    VLOAD(kt0);
    KDMA(kt0);
    VWRITE();
    __syncthreads();

    for (int it = 0; it < ktn; ++it) {
        const int kt = kt0 + it;
        const int k0 = kt * 64;

        if (it + 1 < ktn) VLOAD(kt + 1);       // V global latency hides under QK+SM+PV

        // ---- S^T = K . Q^T - Mlog  (C operand carries -Mlog) ----
        f32x4 st[4];
        __builtin_amdgcn_s_setprio(1);
        #pragma unroll
        for (int mt = 0; mt < 4; ++mt) {
            const int kvr = mt * 16 + c;
            bf16x8 ka = *(const bf16x8*)((const char*)Kl + kvr * 128 + ((g * 16) ^ swz(kvr)));
            bf16x8 kb = *(const bf16x8*)((const char*)Kl + kvr * 128 + ((64 + g * 16) ^ swz(kvr)));
            f32x4 zz = __builtin_amdgcn_mfma_f32_16x16x32_bf16(ka, qf0, negM4, 0, 0, 0);
            st[mt] = __builtin_amdgcn_mfma_f32_16x16x32_bf16(kb, qf1, zz, 0, 0, 0);
        }
        __builtin_amdgcn_s_setprio(0);

        __syncthreads();                       // all waves done reading Kl
        if (it + 1 < ktn) KDMA(kt + 1);        // overlaps with SM+PV

        // ---- softmax: p = 2^st (fixed max, no tracking, no per-tile shfl) ----
        if (causal && (k0 + 63 > q0 + w * 16)) {
            #pragma unroll
            for (int mt = 0; mt < 4; ++mt)
                #pragma unroll
                for (int r = 0; r < 4; ++r)
                    if (k0 + mt * 16 + g * 4 + r > qg) st[mt][r] = -INFINITY;
        }
        {
            float rs = 0.0f;
            #pragma unroll
            for (int mt = 0; mt < 4; ++mt) {
                const float e0 = fast_exp2(st[mt][0]);
                const float e1 = fast_exp2(st[mt][1]);
                const float e2 = fast_exp2(st[mt][2]);
                const float e3 = fast_exp2(st[mt][3]);
                rs += (e0 + e1) + (e2 + e3);
                uint2 u;
                u.x = cvt_pk_bf16(e0, e1);
                u.y = cvt_pk_bf16(e2, e3);
                *(uint2*)((char*)Pl[w] + c * 128 + ((mt * 32 + g * 8) ^ swz(c))) = u;
            }
            l += rs;                           // per-lane partial only
        }

        // ---- PV: out^T += V^T . P^T ----
        __builtin_amdgcn_s_setprio(1);
        #pragma unroll
        for (int kc = 0; kc < 2; ++kc) {
            bf16x8 pb = *(const bf16x8*)((const char*)Pl[w] + c * 128 + ((kc * 64 + g * 16) ^ swz(c)));
            #pragma unroll
            for (int dt = 0; dt < 4; ++dt) {
                const int d = dt * 16 + c;
                bf16x8 vf = *(const bf16x8*)((const char*)VTl + d * 128 + ((kc * 64 + g * 16) ^ swz(d)));
                acc[dt] = __builtin_amdgcn_mfma_f32_16x16x32_bf16(vf, pb, acc[dt], 0, 0, 0);
            }
        }
        __builtin_amdgcn_s_setprio(0);

        __syncthreads();                       // VTl free for rewrite; vmcnt drained
        if (it + 1 < ktn) VWRITE();            // published by next iteration's bar1
    }

    // ---- epilogue ----
    l += __shfl_xor(l, 16);
    l += __shfl_xor(l, 32);

    if (!causal && z == 0) {
        // fold in the self term (split 0 only); qf is log2e-scaled -> ss in log2
        float ssv = 0.0f;
        {
            const short* krow = qkv + (size_t)qg * QKVN + kcol;
            bf16x8 k0s = *(const bf16x8*)(krow + g * 8);
            bf16x8 k1s = *(const bf16x8*)(krow + 32 + g * 8);
            #pragma unroll
            for (int j = 0; j < 8; ++j)
                ssv += bf2f(qf0[j]) * bf2f(k0s[j]) + bf2f(qf1[j]) * bf2f(k1s[j]);
            ssv += __shfl_xor(ssv, 16);
            ssv += __shfl_xor(ssv, 32);
        }
        const float ps = fast_exp2(ssv - Mlog);
        const short* vrow = qkv + (size_t)qg * QKVN + vcol;
        #pragma unroll
        for (int dt = 0; dt < 4; ++dt) {
            bf16x4 vs = *(const bf16x4*)(vrow + dt * 16 + g * 4);
            #pragma unroll
            for (int r = 0; r < 4; ++r)
                acc[dt][r] += ps * bf2f(vs[r]);
        }
        l += ps;
    }

    if (causal && NS == 1) {
        const float inv = 1.0f / l;
        short* orow = attn + (size_t)qg * DMODEL + qcol;
        #pragma unroll
        for (int dt = 0; dt < 4; ++dt)
            #pragma unroll
            for (int r = 0; r < 4; ++r)
                orow[dt * 16 + g * 4 + r] = f2bf(acc[dt][r] * inv);
    } else if (z == 0) {
        float* pml0 = causal ? pml0_c : pml0_q;
        const int stride = causal ? 2048 : 1024;
        const int base   = causal ? 1024 : SPOKES;
        short* orow = attn + (size_t)qg * DMODEL + qcol;
        #pragma unroll
        for (int dt = 0; dt < 4; ++dt)
            #pragma unroll
            for (int r = 0; r < 4; ++r)
                orow[dt * 16 + g * 4 + r] = f2bf(acc[dt][r]);
        if (g == 0) {
            float* p = pml0 + ((size_t)h * stride + (qg - base)) * 2;
            p[0] = Mlog;
            p[1] = l;
        }
    } else {
        const int slot = causal ? (qt < 32 ? qt - 16 : 16 + (qt - 32) * 2 + (z - 1))
                                : qb * 2 + (z - 1);
        short* pacc = causal ? pacc_c : pacc_q;
        float* pml  = causal ? pml_c  : pml_q;
        const int rl = w * 16 + c;            // row within 64-row block
        short* prow = pacc + ((size_t)slot * 64 + rl) * DMODEL + qcol;
        #pragma unroll
        for (int dt = 0; dt < 4; ++dt)
            #pragma unroll
            for (int r = 0; r < 4; ++r)
                prow[dt * 16 + g * 4 + r] = f2bf(acc[dt][r]);
        if (g == 0) {
            float* p = pml + ((size_t)(slot * 16 + h) * 64 + rl) * 2;
            p[0] = Mlog;
            p[1] = l;
        }
    }
}

// ---------------------------------------------------------------------------
// Merged combine (one launch; 64-row slots; r13 configuration).
// ---------------------------------------------------------------------------
__global__ __launch_bounds__(256) void attn_combine_all(
    short* __restrict__ attn,
    const float* __restrict__ pml0_c, const short* __restrict__ pacc_c, const float* __restrict__ pml_c,
    const float* __restrict__ pml0_q, const short* __restrict__ pacc_q, const float* __restrict__ pml_q)
{
    const int gi = blockIdx.x * 256 + threadIdx.x;   // 3 x 131072 threads
    const int seg = gi >> 17;
    const int li  = gi & 131071;
    const int r = li >> 7;
    const int h = (li >> 3) & 15;
    const int o = li & 7;

    int rowbase, pml0_stride, pml0_off, slotBase, slotMul, nextra;
    const float* pml0; const short* pacc; const float* pml;
    if (seg == 0) {
        rowbase = 1024;   pml0_stride = 2048; pml0_off = 0;
        slotBase = 0;  slotMul = 1; nextra = 1;
        pml0 = pml0_c; pacc = pacc_c; pml = pml_c;
    } else if (seg == 1) {
        rowbase = 2048;   pml0_stride = 2048; pml0_off = 1024;
        slotBase = 16; slotMul = 2; nextra = 2;
        pml0 = pml0_c; pacc = pacc_c; pml = pml_c;
    } else {
        rowbase = SPOKES; pml0_stride = 1024; pml0_off = 0;
        slotBase = 0;  slotMul = 2; nextra = 2;
        pml0 = pml0_q; pacc = pacc_q; pml = pml_q;
    }

    const float* p0 = pml0 + ((size_t)h * pml0_stride + pml0_off + r) * 2;
    const float m0 = p0[0], l0 = p0[1];
    float M = m0;
    float me[2], le[2];
    for (int e = 0; e < nextra; ++e) {
        const int slot = slotBase + (r >> 6) * slotMul + e;
        const float* p = pml + ((size_t)(slot * 16 + h) * 64 + (r & 63)) * 2;
        me[e] = p[0]; le[e] = p[1];
        M = fmaxf(M, me[e]);
    }
    const float w0 = __expf(m0 - M);
    float L = w0 * l0;
    float we[2];
    for (int e = 0; e < nextra; ++e) { we[e] = __expf(me[e] - M); L += we[e] * le[e]; }

    short* arow = attn + (size_t)(rowbase + r) * DMODEL + h * 64 + o * 8;
    bf16x8 a0 = *(const bf16x8*)arow;
    float outv[8];
    #pragma unroll
    for (int j = 0; j < 8; ++j) outv[j] = w0 * bf2f(a0[j]);
    for (int e = 0; e < nextra; ++e) {
        const int slot = slotBase + (r >> 6) * slotMul + e;
        bf16x8 a = *(const bf16x8*)(pacc + ((size_t)slot * 64 + (r & 63)) * DMODEL + h * 64 + o * 8);
        #pragma unroll
        for (int j = 0; j < 8; ++j) outv[j] += we[e] * bf2f(a[j]);
    }
    const float inv = 1.0f / L;
    bf16x8 res;
    #pragma unroll
    for (int j = 0; j < 8; ++j) res[j] = f2bf(outv[j] * inv);
    *(bf16x8*)arow = res;
}

// ---------------------------------------------------------------------------
extern "C" void kernel_launch(void* const* d_in, const int* in_sizes, int n_in,
                              void* d_out, int out_size, void* d_ws, size_t ws_size,
                              hipStream_t stream)
{
    const float* x      = (const float*)d_in[0];
    const float* pos    = (const float*)d_in[1];
    const float* qkv_w  = (const float*)d_in[2];
    const float* out_w  = (const float*)d_in[3];
    const float* scale  = (const float*)d_in[4];
    const float* freqs  = (const float*)d_in[5];
    float*       out    = (float*)d_out;

    const size_t MB = 1024 * 1024;
    char* ws = (char*)d_ws;
    short* qkv_bf  = (short*)(ws);                       // [0,24MB)  qkv (live)
    short* x_bf    = (short*)(ws + 24 * MB);             // [24,32)   x -> attn (alias)
    short* wqkv_bf = (short*)(ws + 32 * MB);             // [32,38)   qkv_w -> query partials
    short* wout_bf = (short*)(ws + 38 * MB);             // [38,40)   out_w (live)
    short* pacc_c  = (short*)(ws + 40 * MB);             // [40,46)   48 slots x 64 x 1024 bf16 = 6MB
    float* pml_c   = (float*)(ws + 46 * MB);             // 393216 B  (48 slots x 16h x 64 x 2)
    float* pml0_c  = (float*)(ws + 46 * MB + 393216);    // 262144 B  (ends ~46.63MB)
    short* attn_bf = x_bf;                               // alias (x dead after gemm1)
    short* pacc_q  = wqkv_bf;                            // 32 slots x 64 x 1024 bf16 = 4MB
    float* pml_q   = (float*)((char*)wqkv_bf + 4194304); // 262144 B
    float* pml0_q  = (float*)((char*)wqkv_bf + 4456448); // 131072 B (ends ~36.4MB)

    const dim3 blk(256);

    // 0) single merged f32->bf16 conversion (x, qkv_w, out_w)
    cvt_all<<<dim3((CVT_N0 + CVT_N1 + CVT_N2) / 256), blk, 0, stream>>>(
        x, qkv_w, out_w, x_bf, wqkv_bf, wout_bf);

    // 1) qkv = x @ qkv_w^T with FUSED cos-scale + RoPE (+log2e on q) epilogue
    gemm_bf16<true, true><<<dim3(QKVN / 128, SEQL / 128), blk, 0, stream>>>(
        x_bf, wqkv_bf, qkv_bf, DMODEL, QKVN, pos, scale, freqs);

    // 2) fused attention (r13 best configuration)
    attn_fused<<<dim3(144, NH), blk, 0, stream>>>(
        qkv_bf, scale, attn_bf, pacc_c, pml_c, pml0_c, pacc_q, pml_q, pml0_q);

    // 3) single merged combine
    attn_combine_all<<<dim3(1536), blk, 0, stream>>>(
        attn_bf, pml0_c, pacc_c, pml_c, pml0_q, pacc_q, pml_q);

    // 4) out = attn @ out_w^T  (bf16 in, f32 out)
    gemm_bf16<false, false><<<dim3(DMODEL / 128, SEQL / 128), blk, 0, stream>>>(
        attn_bf, wout_bf, out, DMODEL, DMODEL, nullptr, nullptr, nullptr);
}

// Round 18
// 168.780 us; speedup vs baseline: 2.5677x; 2.5677x over previous
//
#include <hip/hip_runtime.h>
#include <math.h>

#define SEQL   4096
#define DMODEL 1024
#define NH     16
#define DHEAD  64
#define SPOKES 3072
#define NQUERY (SEQL - SPOKES)     // 1024
#define QKVN   (3 * DMODEL)        // 3072
#define LOG2E  1.4426950408889634f

typedef short bf16x8 __attribute__((ext_vector_type(8)));
typedef short bf16x4 __attribute__((ext_vector_type(4)));
typedef float f32x4  __attribute__((ext_vector_type(4)));

__device__ __forceinline__ short f2bf(float f) {
    unsigned u = __builtin_bit_cast(unsigned, f);
    u += 0x7fffu + ((u >> 16) & 1u);     // RNE
    return (short)(u >> 16);
}
__device__ __forceinline__ float bf2f(short s) {
    unsigned u = ((unsigned)(unsigned short)s) << 16;
    return __builtin_bit_cast(float, u);
}
// packed f32x2 -> bf16x2 (RNE), low half = lo
__device__ __forceinline__ unsigned cvt_pk_bf16(float lo, float hi) {
    unsigned u;
    asm("v_cvt_pk_bf16_f32 %0, %1, %2" : "=v"(u) : "v"(lo), "v"(hi));
    return u;
}
// raw 2^x (v_exp_f32); input here is always <= 0 or -inf
__device__ __forceinline__ float fast_exp2(float x) {
#if __has_builtin(__builtin_amdgcn_exp2f)
    return __builtin_amdgcn_exp2f(x);
#else
    float r; asm("v_exp_f32 %0, %1" : "=v"(r) : "v"(x)); return r;
#endif
}
// XOR swizzle on byte bits 4..6, keyed by LDS row (rows are 128B).
__device__ __forceinline__ int swz(int row) { return ((row & 7) ^ (row >> 3)) << 4; }

// async global->LDS, 16B per lane; LDS dest = wave-uniform base + lane*16
__device__ __forceinline__ void gload_lds16(const void* g, void* l) {
    __builtin_amdgcn_global_load_lds(
        (const __attribute__((address_space(1))) unsigned int*)g,
        (__attribute__((address_space(3))) unsigned int*)l,
        16, 0, 0);
}

// ---------------------------------------------------------------------------
// Merged f32 -> bf16 conversion for x, qkv_w, out_w (one launch)
// ---------------------------------------------------------------------------
#define CVT_N0 (SEQL * DMODEL / 8)     // 524288
#define CVT_N1 (QKVN * DMODEL / 8)     // 393216
#define CVT_N2 (DMODEL * DMODEL / 8)   // 131072
__global__ __launch_bounds__(256) void cvt_all(
    const float* __restrict__ x, const float* __restrict__ wq, const float* __restrict__ wo,
    short* __restrict__ xb, short* __restrict__ wqb, short* __restrict__ wob)
{
    int i = blockIdx.x * 256 + threadIdx.x;       // [0, CVT_N0+CVT_N1+CVT_N2)
    const float* src; short* dst;
    if (i < CVT_N0)               { src = x;  dst = xb; }
    else if (i < CVT_N0 + CVT_N1) { src = wq; dst = wqb; i -= CVT_N0; }
    else                          { src = wo; dst = wob; i -= CVT_N0 + CVT_N1; }
    float4 a = ((const float4*)src)[i * 2];
    float4 b = ((const float4*)src)[i * 2 + 1];
    bf16x8 v;
    v[0] = f2bf(a.x); v[1] = f2bf(a.y); v[2] = f2bf(a.z); v[3] = f2bf(a.w);
    v[4] = f2bf(b.x); v[5] = f2bf(b.y); v[6] = f2bf(b.z); v[7] = f2bf(b.w);
    ((bf16x8*)dst)[i] = v;
}

// ---------------------------------------------------------------------------
// bf16 MFMA GEMM: C = A * B^T, 128x128 tile, BK=64.
// FUSE (gemm1 only): cos-scale + axial RoPE (+ log2e on q) in the epilogue.
// r17 lesson: cosf/sinf are NON-INLINED libm calls -> ABI register clamp ->
// accumulator spill (420 us, 1.27 GB scratch writes). Use the inlined HW
// intrinsics __cosf/__sinf (v_cos_f32/v_sin_f32; |theta|<=10pi ~ 5 revs is
// in range, ~1e-6 abs error, negligible vs bf16 rounding).
// ---------------------------------------------------------------------------
template<bool BF16OUT, bool FUSE>
__global__ __launch_bounds__(256) void gemm_bf16(
    const short* __restrict__ A, const short* __restrict__ B, void* __restrict__ Cv,
    int K, int ldc,
    const float* __restrict__ pos, const float* __restrict__ scale,
    const float* __restrict__ freqs)
{
    __shared__ short As[128 * 64];
    __shared__ short Bs[128 * 64];

    const int t = threadIdx.x;
    const int lane = t & 63, w = t >> 6;
    const int c = lane & 15, g = lane >> 4;
    const int wr = w >> 1, wc = w & 1;
    const int m0 = blockIdx.y * 128, n0 = blockIdx.x * 128;

    f32x4 acc[4][4] = {};

    for (int k0 = 0; k0 < K; k0 += 64) {
        __syncthreads();
        #pragma unroll
        for (int i = 0; i < 4; ++i) {
            const int chunk = (w * 4 + i) * 64 + lane;
            const int row = chunk >> 3, cc = chunk & 7;
            gload_lds16(A + (size_t)(m0 + row) * K + k0 + cc * 8,
                        As + (size_t)(w * 4 + i) * 512);
            gload_lds16(B + (size_t)(n0 + row) * K + k0 + cc * 8,
                        Bs + (size_t)(w * 4 + i) * 512);
        }
        __syncthreads();

        #pragma unroll
        for (int kk = 0; kk < 2; ++kk) {
            bf16x8 af[4], bf[4];
            #pragma unroll
            for (int i = 0; i < 4; ++i)
                af[i] = *(const bf16x8*)(As + (wr * 64 + i * 16 + c) * 64 + kk * 32 + g * 8);
            #pragma unroll
            for (int j = 0; j < 4; ++j)
                bf[j] = *(const bf16x8*)(Bs + (wc * 64 + j * 16 + c) * 64 + kk * 32 + g * 8);
            #pragma unroll
            for (int i = 0; i < 4; ++i)
                #pragma unroll
                for (int j = 0; j < 4; ++j)
                    acc[i][j] = __builtin_amdgcn_mfma_f32_16x16x32_bf16(af[i], bf[j], acc[i][j], 0, 0, 0);
        }
    }

    if (FUSE && n0 < 2048) {               // q or k column tile (block-uniform)
        const bool isq = (n0 < 1024);
        const int h = ((n0 >> 6) + wc) & 15;         // this wave-half's head
        const float ss = sqrtf(fabsf(scale[h]) + 1e-8f);
        const float fA = freqs[256 + h * 16 + c];    // dim c      (theta from pos_y)
        const float fB = freqs[h * 16 + c];          // dim 16+c   (theta from pos_x)
        #pragma unroll
        for (int i = 0; i < 4; ++i)
            #pragma unroll
            for (int r = 0; r < 4; ++r) {
                const int row = m0 + wr * 64 + i * 16 + g * 4 + r;
                float a0 = acc[i][0][r], a1 = acc[i][1][r];
                float a2 = acc[i][2][r], a3 = acc[i][3][r];
                float sq = a0 * a0 + a1 * a1 + a2 * a2 + a3 * a3;
                sq += __shfl_xor(sq, 1);
                sq += __shfl_xor(sq, 2);
                sq += __shfl_xor(sq, 4);
                sq += __shfl_xor(sq, 8);             // sum over the 16 c-lanes
                const float f = ss * rsqrtf(sq + 1e-8f);
                a0 *= f; a1 *= f; a2 *= f; a3 *= f;
                const float px = pos[row * 2 + 0];
                const float py = pos[row * 2 + 1];
                const float thA = (py * 2.0f - 1.0f) * fA;
                const float thB = (px * 2.0f - 1.0f) * fB;
                const float cA = __cosf(thA), sA = __sinf(thA);
                const float cB = __cosf(thB), sB = __sinf(thB);
                float n0v = a0 * cA - a2 * sA;       // dim c
                float n2v = a2 * cA + a0 * sA;       // dim 32+c
                float n1v = a1 * cB - a3 * sB;       // dim 16+c
                float n3v = a3 * cB + a1 * sB;       // dim 48+c
                if (isq) { n0v *= LOG2E; n1v *= LOG2E; n2v *= LOG2E; n3v *= LOG2E; }
                acc[i][0][r] = n0v; acc[i][1][r] = n1v;
                acc[i][2][r] = n2v; acc[i][3][r] = n3v;
            }
    }

    #pragma unroll
    for (int i = 0; i < 4; ++i)
        #pragma unroll
        for (int r = 0; r < 4; ++r) {
            const int row = m0 + wr * 64 + i * 16 + g * 4 + r;
            #pragma unroll
            for (int j = 0; j < 4; ++j) {
                const int col = n0 + wc * 64 + j * 16 + c;
                const float v = acc[i][j][r];
                if (BF16OUT) ((short*)Cv)[(size_t)row * ldc + col] = f2bf(v);
                else         ((float*)Cv)[(size_t)row * ldc + col] = v;
            }
        }
}

// ---------------------------------------------------------------------------
// Fused flash attention (r13 configuration — best measured):
// 4 waves x 16 q rows = 64 q rows / block, KVBLK=64, single-buffered K/V
// (24 KB LDS), two barriers per tile, fixed-max softmax, deferred l reduce.
// grid = (144, 16).
// ---------------------------------------------------------------------------
__global__ __launch_bounds__(256) void attn_fused(
    const short* __restrict__ qkv, const float* __restrict__ scale,
    short* __restrict__ attn,
    short* __restrict__ pacc_c, float* __restrict__ pml_c, float* __restrict__ pml0_c,
    short* __restrict__ pacc_q, float* __restrict__ pml_q, float* __restrict__ pml0_q)
{
    __shared__ short Kl[64 * 64];          // 8 KB
    __shared__ short VTl[64 * 64];         // 8 KB
    __shared__ short Pl[4][16 * 64];       // 8 KB

    const int h = blockIdx.y;
    const int t = threadIdx.x, lane = t & 63, w = t >> 6;
    const int c = lane & 15, g = lane >> 4;
    const int qcol = h * DHEAD, kcol = DMODEL + h * DHEAD, vcol = 2 * DMODEL + h * DHEAD;

    // ---- decode chunk ----
    const int xc = blockIdx.x;
    bool causal; int z, NS, q0, kt0, ktn, qt = 0, qb = 0;
    if (xc < 48) {
        causal = false; qb = xc / 3; z = xc - qb * 3; NS = 3;
        q0 = SPOKES + qb * 64; kt0 = z * 16; ktn = 16;
    } else {
        causal = true;
        if (xc < 96)       { const int i = xc - 48; qt = 47 - i / 3; z = i - (i / 3) * 3; NS = 3; }
        else if (xc < 128) { const int i = xc - 96; qt = 31 - (i >> 1); z = i & 1; NS = 2; }
        else               { qt = 143 - xc; z = 0; NS = 1; }
        q0 = qt * 64;
        const int full = qt + 1, b = full / NS, r = full - b * NS;
        kt0 = z * b + (z < r ? z : r);
        ktn = b + (z < r ? 1 : 0);
    }

    const int qg = q0 + w * 16 + c;       // this lane's q row

    // fixed softmax max in log2 domain
    const float Mlog = (fabsf(scale[h]) * 1.02f + 0.5f) * LOG2E;
    const f32x4 negM4 = {-Mlog, -Mlog, -Mlog, -Mlog};

    bf16x8 qf0, qf1;
    {
        const short* qrow = qkv + (size_t)qg * QKVN + qcol;
        qf0 = *(const bf16x8*)(qrow + g * 8);
        qf1 = *(const bf16x8*)(qrow + 32 + g * 8);
    }

    float l = 0.0f;                        // per-lane partial (reduced in epilogue)
    f32x4 acc[4] = {};
    bf16x8 vregA, vregB;

    // ---- staging helpers (single buffer) ----
    auto KDMA = [&](int kt) {
        const int k0 = kt * 64;
        #pragma unroll
        for (int i = 0; i < 2; ++i) {
            const int ch = i * 256 + t;                 // 16B chunk index
            const int kv = ch >> 3, s = ch & 7;
            const int o = s ^ ((kv & 7) ^ (kv >> 3));   // pre-swizzled source octet
            gload_lds16(qkv + (size_t)(k0 + kv) * QKVN + kcol + o * 8,
                        (char*)Kl + i * 4096 + w * 1024);
        }
    };
    auto VLOAD = [&](int kt) {
        const int k0 = kt * 64;
        const short* vv = qkv + (size_t)(k0 + 2 * (t >> 3)) * QKVN + vcol + (t & 7) * 8;
        vregA = *(const bf16x8*)vv;
        vregB = *(const bf16x8*)(vv + QKVN);
    };
    auto VWRITE = [&]() {
        const int p2 = t >> 3, oc = t & 7;
        #pragma unroll
        for (int j = 0; j < 8; ++j) {
            const int d = oc * 8 + j;
            const unsigned u = ((unsigned)(unsigned short)vregA[j]) |
                               (((unsigned)(unsigned short)vregB[j]) << 16);
            *(unsigned*)((char*)VTl + d * 128 + ((4 * p2) ^ swz(d))) = u;
        }
    };

    // ---- prologue: stage tile kt0 ----
    VLOAD(kt0);
    KDMA(kt0);
    VWRITE();
    __syncthreads();

    for (int it = 0; it < ktn; ++it) {
        const int kt = kt0 + it;
        const int k0 = kt * 64;

        if (it + 1 < ktn) VLOAD(kt + 1);       // V global latency hides under QK+SM+PV

        // ---- S^T = K . Q^T - Mlog  (C operand carries -Mlog) ----
        f32x4 st[4];
        __builtin_amdgcn_s_setprio(1);
        #pragma unroll
        for (int mt = 0; mt < 4; ++mt) {
            const int kvr = mt * 16 + c;
            bf16x8 ka = *(const bf16x8*)((const char*)Kl + kvr * 128 + ((g * 16) ^ swz(kvr)));
            bf16x8 kb = *(const bf16x8*)((const char*)Kl + kvr * 128 + ((64 + g * 16) ^ swz(kvr)));
            f32x4 zz = __builtin_amdgcn_mfma_f32_16x16x32_bf16(ka, qf0, negM4, 0, 0, 0);
            st[mt] = __builtin_amdgcn_mfma_f32_16x16x32_bf16(kb, qf1, zz, 0, 0, 0);
        }
        __builtin_amdgcn_s_setprio(0);

        __syncthreads();                       // all waves done reading Kl
        if (it + 1 < ktn) KDMA(kt + 1);        // overlaps with SM+PV

        // ---- softmax: p = 2^st (fixed max, no tracking, no per-tile shfl) ----
        if (causal && (k0 + 63 > q0 + w * 16)) {
            #pragma unroll
            for (int mt = 0; mt < 4; ++mt)
                #pragma unroll
                for (int r = 0; r < 4; ++r)
                    if (k0 + mt * 16 + g * 4 + r > qg) st[mt][r] = -INFINITY;
        }
        {
            float rs = 0.0f;
            #pragma unroll
            for (int mt = 0; mt < 4; ++mt) {
                const float e0 = fast_exp2(st[mt][0]);
                const float e1 = fast_exp2(st[mt][1]);
                const float e2 = fast_exp2(st[mt][2]);
                const float e3 = fast_exp2(st[mt][3]);
                rs += (e0 + e1) + (e2 + e3);
                uint2 u;
                u.x = cvt_pk_bf16(e0, e1);
                u.y = cvt_pk_bf16(e2, e3);
                *(uint2*)((char*)Pl[w] + c * 128 + ((mt * 32 + g * 8) ^ swz(c))) = u;
            }
            l += rs;                           // per-lane partial only
        }

        // ---- PV: out^T += V^T . P^T ----
        __builtin_amdgcn_s_setprio(1);
        #pragma unroll
        for (int kc = 0; kc < 2; ++kc) {
            bf16x8 pb = *(const bf16x8*)((const char*)Pl[w] + c * 128 + ((kc * 64 + g * 16) ^ swz(c)));
            #pragma unroll
            for (int dt = 0; dt < 4; ++dt) {
                const int d = dt * 16 + c;
                bf16x8 vf = *(const bf16x8*)((const char*)VTl + d * 128 + ((kc * 64 + g * 16) ^ swz(d)));
                acc[dt] = __builtin_amdgcn_mfma_f32_16x16x32_bf16(vf, pb, acc[dt], 0, 0, 0);
            }
        }
        __builtin_amdgcn_s_setprio(0);

        __syncthreads();                       // VTl free for rewrite; vmcnt drained
        if (it + 1 < ktn) VWRITE();            // published by next iteration's bar1
    }

    // ---- epilogue ----
    l += __shfl_xor(l, 16);
    l += __shfl_xor(l, 32);

    if (!causal && z == 0) {
        // fold in the self term (split 0 only); qf is log2e-scaled -> ss in log2
        float ssv = 0.0f;
        {
            const short* krow = qkv + (size_t)qg * QKVN + kcol;
            bf16x8 k0s = *(const bf16x8*)(krow + g * 8);
            bf16x8 k1s = *(const bf16x8*)(krow + 32 + g * 8);
            #pragma unroll
            for (int j = 0; j < 8; ++j)
                ssv += bf2f(qf0[j]) * bf2f(k0s[j]) + bf2f(qf1[j]) * bf2f(k1s[j]);
            ssv += __shfl_xor(ssv, 16);
            ssv += __shfl_xor(ssv, 32);
        }
        const float ps = fast_exp2(ssv - Mlog);
        const short* vrow = qkv + (size_t)qg * QKVN + vcol;
        #pragma unroll
        for (int dt = 0; dt < 4; ++dt) {
            bf16x4 vs = *(const bf16x4*)(vrow + dt * 16 + g * 4);
            #pragma unroll
            for (int r = 0; r < 4; ++r)
                acc[dt][r] += ps * bf2f(vs[r]);
        }
        l += ps;
    }

    if (causal && NS == 1) {
        const float inv = 1.0f / l;
        short* orow = attn + (size_t)qg * DMODEL + qcol;
        #pragma unroll
        for (int dt = 0; dt < 4; ++dt)
            #pragma unroll
            for (int r = 0; r < 4; ++r)
                orow[dt * 16 + g * 4 + r] = f2bf(acc[dt][r] * inv);
    } else if (z == 0) {
        float* pml0 = causal ? pml0_c : pml0_q;
        const int stride = causal ? 2048 : 1024;
        const int base   = causal ? 1024 : SPOKES;
        short* orow = attn + (size_t)qg * DMODEL + qcol;
        #pragma unroll
        for (int dt = 0; dt < 4; ++dt)
            #pragma unroll
            for (int r = 0; r < 4; ++r)
                orow[dt * 16 + g * 4 + r] = f2bf(acc[dt][r]);
        if (g == 0) {
            float* p = pml0 + ((size_t)h * stride + (qg - base)) * 2;
            p[0] = Mlog;
            p[1] = l;
        }
    } else {
        const int slot = causal ? (qt < 32 ? qt - 16 : 16 + (qt - 32) * 2 + (z - 1))
                                : qb * 2 + (z - 1);
        short* pacc = causal ? pacc_c : pacc_q;
        float* pml  = causal ? pml_c  : pml_q;
        const int rl = w * 16 + c;            // row within 64-row block
        short* prow = pacc + ((size_t)slot * 64 + rl) * DMODEL + qcol;
        #pragma unroll
        for (int dt = 0; dt < 4; ++dt)
            #pragma unroll
            for (int r = 0; r < 4; ++r)
                prow[dt * 16 + g * 4 + r] = f2bf(acc[dt][r]);
        if (g == 0) {
            float* p = pml + ((size_t)(slot * 16 + h) * 64 + rl) * 2;
            p[0] = Mlog;
            p[1] = l;
        }
    }
}

// ---------------------------------------------------------------------------
// Merged combine (one launch; 64-row slots).
// ---------------------------------------------------------------------------
__global__ __launch_bounds__(256) void attn_combine_all(
    short* __restrict__ attn,
    const float* __restrict__ pml0_c, const short* __restrict__ pacc_c, const float* __restrict__ pml_c,
    const float* __restrict__ pml0_q, const short* __restrict__ pacc_q, const float* __restrict__ pml_q)
{
    const int gi = blockIdx.x * 256 + threadIdx.x;   // 3 x 131072 threads
    const int seg = gi >> 17;
    const int li  = gi & 131071;
    const int r = li >> 7;
    const int h = (li >> 3) & 15;
    const int o = li & 7;

    int rowbase, pml0_stride, pml0_off, slotBase, slotMul, nextra;
    const float* pml0; const short* pacc; const float* pml;
    if (seg == 0) {
        rowbase = 1024;   pml0_stride = 2048; pml0_off = 0;
        slotBase = 0;  slotMul = 1; nextra = 1;
        pml0 = pml0_c; pacc = pacc_c; pml = pml_c;
    } else if (seg == 1) {
        rowbase = 2048;   pml0_stride = 2048; pml0_off = 1024;
        slotBase = 16; slotMul = 2; nextra = 2;
        pml0 = pml0_c; pacc = pacc_c; pml = pml_c;
    } else {
        rowbase = SPOKES; pml0_stride = 1024; pml0_off = 0;
        slotBase = 0;  slotMul = 2; nextra = 2;
        pml0 = pml0_q; pacc = pacc_q; pml = pml_q;
    }

    const float* p0 = pml0 + ((size_t)h * pml0_stride + pml0_off + r) * 2;
    const float m0 = p0[0], l0 = p0[1];
    float M = m0;
    float me[2], le[2];
    for (int e = 0; e < nextra; ++e) {
        const int slot = slotBase + (r >> 6) * slotMul + e;
        const float* p = pml + ((size_t)(slot * 16 + h) * 64 + (r & 63)) * 2;
        me[e] = p[0]; le[e] = p[1];
        M = fmaxf(M, me[e]);
    }
    const float w0 = __expf(m0 - M);
    float L = w0 * l0;
    float we[2];
    for (int e = 0; e < nextra; ++e) { we[e] = __expf(me[e] - M); L += we[e] * le[e]; }

    short* arow = attn + (size_t)(rowbase + r) * DMODEL + h * 64 + o * 8;
    bf16x8 a0 = *(const bf16x8*)arow;
    float outv[8];
    #pragma unroll
    for (int j = 0; j < 8; ++j) outv[j] = w0 * bf2f(a0[j]);
    for (int e = 0; e < nextra; ++e) {
        const int slot = slotBase + (r >> 6) * slotMul + e;
        bf16x8 a = *(const bf16x8*)(pacc + ((size_t)slot * 64 + (r & 63)) * DMODEL + h * 64 + o * 8);
        #pragma unroll
        for (int j = 0; j < 8; ++j) outv[j] += we[e] * bf2f(a[j]);
    }
    const float inv = 1.0f / L;
    bf16x8 res;
    #pragma unroll
    for (int j = 0; j < 8; ++j) res[j] = f2bf(outv[j] * inv);
    *(bf16x8*)arow = res;
}

// ---------------------------------------------------------------------------
extern "C" void kernel_launch(void* const* d_in, const int* in_sizes, int n_in,
                              void* d_out, int out_size, void* d_ws, size_t ws_size,
                              hipStream_t stream)
{
    const float* x      = (const float*)d_in[0];
    const float* pos    = (const float*)d_in[1];
    const float* qkv_w  = (const float*)d_in[2];
    const float* out_w  = (const float*)d_in[3];
    const float* scale  = (const float*)d_in[4];
    const float* freqs  = (const float*)d_in[5];
    float*       out    = (float*)d_out;

    const size_t MB = 1024 * 1024;
    char* ws = (char*)d_ws;
    short* qkv_bf  = (short*)(ws);                       // [0,24MB)  qkv (live)
    short* x_bf    = (short*)(ws + 24 * MB);             // [24,32)   x -> attn (alias)
    short* wqkv_bf = (short*)(ws + 32 * MB);             // [32,38)   qkv_w -> query partials
    short* wout_bf = (short*)(ws + 38 * MB);             // [38,40)   out_w (live)
    short* pacc_c  = (short*)(ws + 40 * MB);             // [40,46)   48 slots x 64 x 1024 bf16 = 6MB
    float* pml_c   = (float*)(ws + 46 * MB);             // 393216 B  (48 slots x 16h x 64 x 2)
    float* pml0_c  = (float*)(ws + 46 * MB + 393216);    // 262144 B  (ends ~46.63MB)
    short* attn_bf = x_bf;                               // alias (x dead after gemm1)
    short* pacc_q  = wqkv_bf;                            // 32 slots x 64 x 1024 bf16 = 4MB
    float* pml_q   = (float*)((char*)wqkv_bf + 4194304); // 262144 B
    float* pml0_q  = (float*)((char*)wqkv_bf + 4456448); // 131072 B (ends ~36.4MB)

    const dim3 blk(256);

    // 0) single merged f32->bf16 conversion (x, qkv_w, out_w)
    cvt_all<<<dim3((CVT_N0 + CVT_N1 + CVT_N2) / 256), blk, 0, stream>>>(
        x, qkv_w, out_w, x_bf, wqkv_bf, wout_bf);

    // 1) qkv = x @ qkv_w^T with FUSED cos-scale + RoPE (+log2e on q) epilogue
    gemm_bf16<true, true><<<dim3(QKVN / 128, SEQL / 128), blk, 0, stream>>>(
        x_bf, wqkv_bf, qkv_bf, DMODEL, QKVN, pos, scale, freqs);

    // 2) fused attention (r13 best configuration)
    attn_fused<<<dim3(144, NH), blk, 0, stream>>>(
        qkv_bf, scale, attn_bf, pacc_c, pml_c, pml0_c, pacc_q, pml_q, pml0_q);

    // 3) single merged combine
    attn_combine_all<<<dim3(1536), blk, 0, stream>>>(
        attn_bf, pml0_c, pacc_c, pml_c, pml0_q, pacc_q, pml_q);

    // 4) out = attn @ out_w^T  (bf16 in, f32 out)
    gemm_bf16<false, false><<<dim3(DMODEL / 128, SEQL / 128), blk, 0, stream>>>(
        attn_bf, wout_bf, out, DMODEL, DMODEL, nullptr, nullptr, nullptr);
}

// Round 19
// 168.757 us; speedup vs baseline: 2.5681x; 1.0001x over previous
//
#include <hip/hip_runtime.h>
#include <math.h>

#define SEQL   4096
#define DMODEL 1024
#define NH     16
#define DHEAD  64
#define SPOKES 3072
#define NQUERY (SEQL - SPOKES)     // 1024
#define QKVN   (3 * DMODEL)        // 3072
#define LOG2E  1.4426950408889634f

typedef short bf16x8 __attribute__((ext_vector_type(8)));
typedef short bf16x4 __attribute__((ext_vector_type(4)));
typedef float f32x4  __attribute__((ext_vector_type(4)));

__device__ __forceinline__ short f2bf(float f) {
    unsigned u = __builtin_bit_cast(unsigned, f);
    u += 0x7fffu + ((u >> 16) & 1u);     // RNE
    return (short)(u >> 16);
}
__device__ __forceinline__ float bf2f(short s) {
    unsigned u = ((unsigned)(unsigned short)s) << 16;
    return __builtin_bit_cast(float, u);
}
// packed f32x2 -> bf16x2 (RNE), low half = lo
__device__ __forceinline__ unsigned cvt_pk_bf16(float lo, float hi) {
    unsigned u;
    asm("v_cvt_pk_bf16_f32 %0, %1, %2" : "=v"(u) : "v"(lo), "v"(hi));
    return u;
}
// raw 2^x (v_exp_f32); input here is always <= 0 or -inf
__device__ __forceinline__ float fast_exp2(float x) {
#if __has_builtin(__builtin_amdgcn_exp2f)
    return __builtin_amdgcn_exp2f(x);
#else
    float r; asm("v_exp_f32 %0, %1" : "=v"(r) : "v"(x)); return r;
#endif
}
// XOR swizzle on byte bits 4..6, keyed by LDS row (rows are 128B).
__device__ __forceinline__ int swz(int row) { return ((row & 7) ^ (row >> 3)) << 4; }

// async global->LDS, 16B per lane; LDS dest = wave-uniform base + lane*16
__device__ __forceinline__ void gload_lds16(const void* g, void* l) {
    __builtin_amdgcn_global_load_lds(
        (const __attribute__((address_space(1))) unsigned int*)g,
        (__attribute__((address_space(3))) unsigned int*)l,
        16, 0, 0);
}

// ---------------------------------------------------------------------------
// Merged f32 -> bf16 conversion for x, qkv_w, out_w (one launch)
// ---------------------------------------------------------------------------
#define CVT_N0 (SEQL * DMODEL / 8)     // 524288
#define CVT_N1 (QKVN * DMODEL / 8)     // 393216
#define CVT_N2 (DMODEL * DMODEL / 8)   // 131072
__global__ __launch_bounds__(256) void cvt_all(
    const float* __restrict__ x, const float* __restrict__ wq, const float* __restrict__ wo,
    short* __restrict__ xb, short* __restrict__ wqb, short* __restrict__ wob)
{
    int i = blockIdx.x * 256 + threadIdx.x;       // [0, CVT_N0+CVT_N1+CVT_N2)
    const float* src; short* dst;
    if (i < CVT_N0)               { src = x;  dst = xb; }
    else if (i < CVT_N0 + CVT_N1) { src = wq; dst = wqb; i -= CVT_N0; }
    else                          { src = wo; dst = wob; i -= CVT_N0 + CVT_N1; }
    float4 a = ((const float4*)src)[i * 2];
    float4 b = ((const float4*)src)[i * 2 + 1];
    bf16x8 v;
    v[0] = f2bf(a.x); v[1] = f2bf(a.y); v[2] = f2bf(a.z); v[3] = f2bf(a.w);
    v[4] = f2bf(b.x); v[5] = f2bf(b.y); v[6] = f2bf(b.z); v[7] = f2bf(b.w);
    ((bf16x8*)dst)[i] = v;
}

// ---------------------------------------------------------------------------
// bf16 MFMA GEMM: C = A * B^T, 128x128 tile, BK=64.
// FUSE (gemm1 only): cos-scale + axial RoPE (+ log2e on q) in the epilogue
// using the inlined HW trig intrinsics __cosf/__sinf (libm cosf/sinf are
// non-inlined calls -> ABI register clamp -> accumulator spill; r17 lesson).
// ---------------------------------------------------------------------------
template<bool BF16OUT, bool FUSE>
__global__ __launch_bounds__(256) void gemm_bf16(
    const short* __restrict__ A, const short* __restrict__ B, void* __restrict__ Cv,
    int K, int ldc,
    const float* __restrict__ pos, const float* __restrict__ scale,
    const float* __restrict__ freqs)
{
    __shared__ short As[128 * 64];
    __shared__ short Bs[128 * 64];

    const int t = threadIdx.x;
    const int lane = t & 63, w = t >> 6;
    const int c = lane & 15, g = lane >> 4;
    const int wr = w >> 1, wc = w & 1;
    const int m0 = blockIdx.y * 128, n0 = blockIdx.x * 128;

    f32x4 acc[4][4] = {};

    for (int k0 = 0; k0 < K; k0 += 64) {
        __syncthreads();
        #pragma unroll
        for (int i = 0; i < 4; ++i) {
            const int chunk = (w * 4 + i) * 64 + lane;
            const int row = chunk >> 3, cc = chunk & 7;
            gload_lds16(A + (size_t)(m0 + row) * K + k0 + cc * 8,
                        As + (size_t)(w * 4 + i) * 512);
            gload_lds16(B + (size_t)(n0 + row) * K + k0 + cc * 8,
                        Bs + (size_t)(w * 4 + i) * 512);
        }
        __syncthreads();

        #pragma unroll
        for (int kk = 0; kk < 2; ++kk) {
            bf16x8 af[4], bf[4];
            #pragma unroll
            for (int i = 0; i < 4; ++i)
                af[i] = *(const bf16x8*)(As + (wr * 64 + i * 16 + c) * 64 + kk * 32 + g * 8);
            #pragma unroll
            for (int j = 0; j < 4; ++j)
                bf[j] = *(const bf16x8*)(Bs + (wc * 64 + j * 16 + c) * 64 + kk * 32 + g * 8);
            #pragma unroll
            for (int i = 0; i < 4; ++i)
                #pragma unroll
                for (int j = 0; j < 4; ++j)
                    acc[i][j] = __builtin_amdgcn_mfma_f32_16x16x32_bf16(af[i], bf[j], acc[i][j], 0, 0, 0);
        }
    }

    if (FUSE && n0 < 2048) {               // q or k column tile (block-uniform)
        const bool isq = (n0 < 1024);
        const int h = ((n0 >> 6) + wc) & 15;         // this wave-half's head
        const float ss = sqrtf(fabsf(scale[h]) + 1e-8f);
        const float fA = freqs[256 + h * 16 + c];    // dim c      (theta from pos_y)
        const float fB = freqs[h * 16 + c];          // dim 16+c   (theta from pos_x)
        #pragma unroll
        for (int i = 0; i < 4; ++i)
            #pragma unroll
            for (int r = 0; r < 4; ++r) {
                const int row = m0 + wr * 64 + i * 16 + g * 4 + r;
                float a0 = acc[i][0][r], a1 = acc[i][1][r];
                float a2 = acc[i][2][r], a3 = acc[i][3][r];
                float sq = a0 * a0 + a1 * a1 + a2 * a2 + a3 * a3;
                sq += __shfl_xor(sq, 1);
                sq += __shfl_xor(sq, 2);
                sq += __shfl_xor(sq, 4);
                sq += __shfl_xor(sq, 8);             // sum over the 16 c-lanes
                const float f = ss * rsqrtf(sq + 1e-8f);
                a0 *= f; a1 *= f; a2 *= f; a3 *= f;
                const float px = pos[row * 2 + 0];
                const float py = pos[row * 2 + 1];
                const float thA = (py * 2.0f - 1.0f) * fA;
                const float thB = (px * 2.0f - 1.0f) * fB;
                const float cA = __cosf(thA), sA = __sinf(thA);
                const float cB = __cosf(thB), sB = __sinf(thB);
                float n0v = a0 * cA - a2 * sA;       // dim c
                float n2v = a2 * cA + a0 * sA;       // dim 32+c
                float n1v = a1 * cB - a3 * sB;       // dim 16+c
                float n3v = a3 * cB + a1 * sB;       // dim 48+c
                if (isq) { n0v *= LOG2E; n1v *= LOG2E; n2v *= LOG2E; n3v *= LOG2E; }
                acc[i][0][r] = n0v; acc[i][1][r] = n1v;
                acc[i][2][r] = n2v; acc[i][3][r] = n3v;
            }
    }

    #pragma unroll
    for (int i = 0; i < 4; ++i)
        #pragma unroll
        for (int r = 0; r < 4; ++r) {
            const int row = m0 + wr * 64 + i * 16 + g * 4 + r;
            #pragma unroll
            for (int j = 0; j < 4; ++j) {
                const int col = n0 + wc * 64 + j * 16 + c;
                const float v = acc[i][j][r];
                if (BF16OUT) ((short*)Cv)[(size_t)row * ldc + col] = f2bf(v);
                else         ((float*)Cv)[(size_t)row * ldc + col] = v;
            }
        }
}

// ---------------------------------------------------------------------------
// Fused flash attention (r13 configuration — best measured):
// 4 waves x 16 q rows = 64 q rows / block, KVBLK=64, single-buffered K/V
// (24 KB LDS), two barriers per tile, fixed-max softmax, deferred l reduce.
// grid = (144, 16).
// ---------------------------------------------------------------------------
__global__ __launch_bounds__(256) void attn_fused(
    const short* __restrict__ qkv, const float* __restrict__ scale,
    short* __restrict__ attn,
    short* __restrict__ pacc_c, float* __restrict__ pml_c, float* __restrict__ pml0_c,
    short* __restrict__ pacc_q, float* __restrict__ pml_q, float* __restrict__ pml0_q)
{
    __shared__ short Kl[64 * 64];          // 8 KB
    __shared__ short VTl[64 * 64];         // 8 KB
    __shared__ short Pl[4][16 * 64];       // 8 KB

    const int h = blockIdx.y;
    const int t = threadIdx.x, lane = t & 63, w = t >> 6;
    const int c = lane & 15, g = lane >> 4;
    const int qcol = h * DHEAD, kcol = DMODEL + h * DHEAD, vcol = 2 * DMODEL + h * DHEAD;

    // ---- decode chunk ----
    const int xc = blockIdx.x;
    bool causal; int z, NS, q0, kt0, ktn, qt = 0, qb = 0;
    if (xc < 48) {
        causal = false; qb = xc / 3; z = xc - qb * 3; NS = 3;
        q0 = SPOKES + qb * 64; kt0 = z * 16; ktn = 16;
    } else {
        causal = true;
        if (xc < 96)       { const int i = xc - 48; qt = 47 - i / 3; z = i - (i / 3) * 3; NS = 3; }
        else if (xc < 128) { const int i = xc - 96; qt = 31 - (i >> 1); z = i & 1; NS = 2; }
        else               { qt = 143 - xc; z = 0; NS = 1; }
        q0 = qt * 64;
        const int full = qt + 1, b = full / NS, r = full - b * NS;
        kt0 = z * b + (z < r ? z : r);
        ktn = b + (z < r ? 1 : 0);
    }

    const int qg = q0 + w * 16 + c;       // this lane's q row

    // fixed softmax max in log2 domain
    const float Mlog = (fabsf(scale[h]) * 1.02f + 0.5f) * LOG2E;
    const f32x4 negM4 = {-Mlog, -Mlog, -Mlog, -Mlog};

    bf16x8 qf0, qf1;
    {
        const short* qrow = qkv + (size_t)qg * QKVN + qcol;
        qf0 = *(const bf16x8*)(qrow + g * 8);
        qf1 = *(const bf16x8*)(qrow + 32 + g * 8);
    }

    float l = 0.0f;                        // per-lane partial (reduced in epilogue)
    f32x4 acc[4] = {};
    bf16x8 vregA, vregB;

    // ---- staging helpers (single buffer) ----
    auto KDMA = [&](int kt) {
        const int k0 = kt * 64;
        #pragma unroll
        for (int i = 0; i < 2; ++i) {
            const int ch = i * 256 + t;                 // 16B chunk index
            const int kv = ch >> 3, s = ch & 7;
            const int o = s ^ ((kv & 7) ^ (kv >> 3));   // pre-swizzled source octet
            gload_lds16(qkv + (size_t)(k0 + kv) * QKVN + kcol + o * 8,
                        (char*)Kl + i * 4096 + w * 1024);
        }
    };
    auto VLOAD = [&](int kt) {
        const int k0 = kt * 64;
        const short* vv = qkv + (size_t)(k0 + 2 * (t >> 3)) * QKVN + vcol + (t & 7) * 8;
        vregA = *(const bf16x8*)vv;
        vregB = *(const bf16x8*)(vv + QKVN);
    };
    auto VWRITE = [&]() {
        const int p2 = t >> 3, oc = t & 7;
        #pragma unroll
        for (int j = 0; j < 8; ++j) {
            const int d = oc * 8 + j;
            const unsigned u = ((unsigned)(unsigned short)vregA[j]) |
                               (((unsigned)(unsigned short)vregB[j]) << 16);
            *(unsigned*)((char*)VTl + d * 128 + ((4 * p2) ^ swz(d))) = u;
        }
    };

    // ---- prologue: stage tile kt0 ----
    VLOAD(kt0);
    KDMA(kt0);
    VWRITE();
    __syncthreads();

    for (int it = 0; it < ktn; ++it) {
        const int kt = kt0 + it;
        const int k0 = kt * 64;

        if (it + 1 < ktn) VLOAD(kt + 1);       // V global latency hides under QK+SM+PV

        // ---- S^T = K . Q^T - Mlog  (C operand carries -Mlog) ----
        f32x4 st[4];
        __builtin_amdgcn_s_setprio(1);
        #pragma unroll
        for (int mt = 0; mt < 4; ++mt) {
            const int kvr = mt * 16 + c;
            bf16x8 ka = *(const bf16x8*)((const char*)Kl + kvr * 128 + ((g * 16) ^ swz(kvr)));
            bf16x8 kb = *(const bf16x8*)((const char*)Kl + kvr * 128 + ((64 + g * 16) ^ swz(kvr)));
            f32x4 zz = __builtin_amdgcn_mfma_f32_16x16x32_bf16(ka, qf0, negM4, 0, 0, 0);
            st[mt] = __builtin_amdgcn_mfma_f32_16x16x32_bf16(kb, qf1, zz, 0, 0, 0);
        }
        __builtin_amdgcn_s_setprio(0);

        __syncthreads();                       // all waves done reading Kl
        if (it + 1 < ktn) KDMA(kt + 1);        // overlaps with SM+PV

        // ---- softmax: p = 2^st (fixed max, no tracking, no per-tile shfl) ----
        if (causal && (k0 + 63 > q0 + w * 16)) {
            #pragma unroll
            for (int mt = 0; mt < 4; ++mt)
                #pragma unroll
                for (int r = 0; r < 4; ++r)
                    if (k0 + mt * 16 + g * 4 + r > qg) st[mt][r] = -INFINITY;
        }
        {
            float rs = 0.0f;
            #pragma unroll
            for (int mt = 0; mt < 4; ++mt) {
                const float e0 = fast_exp2(st[mt][0]);
                const float e1 = fast_exp2(st[mt][1]);
                const float e2 = fast_exp2(st[mt][2]);
                const float e3 = fast_exp2(st[mt][3]);
                rs += (e0 + e1) + (e2 + e3);
                uint2 u;
                u.x = cvt_pk_bf16(e0, e1);
                u.y = cvt_pk_bf16(e2, e3);
                *(uint2*)((char*)Pl[w] + c * 128 + ((mt * 32 + g * 8) ^ swz(c))) = u;
            }
            l += rs;                           // per-lane partial only
        }

        // ---- PV: out^T += V^T . P^T ----
        __builtin_amdgcn_s_setprio(1);
        #pragma unroll
        for (int kc = 0; kc < 2; ++kc) {
            bf16x8 pb = *(const bf16x8*)((const char*)Pl[w] + c * 128 + ((kc * 64 + g * 16) ^ swz(c)));
            #pragma unroll
            for (int dt = 0; dt < 4; ++dt) {
                const int d = dt * 16 + c;
                bf16x8 vf = *(const bf16x8*)((const char*)VTl + d * 128 + ((kc * 64 + g * 16) ^ swz(d)));
                acc[dt] = __builtin_amdgcn_mfma_f32_16x16x32_bf16(vf, pb, acc[dt], 0, 0, 0);
            }
        }
        __builtin_amdgcn_s_setprio(0);

        __syncthreads();                       // VTl free for rewrite; vmcnt drained
        if (it + 1 < ktn) VWRITE();            // published by next iteration's bar1
    }

    // ---- epilogue ----
    l += __shfl_xor(l, 16);
    l += __shfl_xor(l, 32);

    if (!causal && z == 0) {
        // fold in the self term (split 0 only); qf is log2e-scaled -> ss in log2
        float ssv = 0.0f;
        {
            const short* krow = qkv + (size_t)qg * QKVN + kcol;
            bf16x8 k0s = *(const bf16x8*)(krow + g * 8);
            bf16x8 k1s = *(const bf16x8*)(krow + 32 + g * 8);
            #pragma unroll
            for (int j = 0; j < 8; ++j)
                ssv += bf2f(qf0[j]) * bf2f(k0s[j]) + bf2f(qf1[j]) * bf2f(k1s[j]);
            ssv += __shfl_xor(ssv, 16);
            ssv += __shfl_xor(ssv, 32);
        }
        const float ps = fast_exp2(ssv - Mlog);
        const short* vrow = qkv + (size_t)qg * QKVN + vcol;
        #pragma unroll
        for (int dt = 0; dt < 4; ++dt) {
            bf16x4 vs = *(const bf16x4*)(vrow + dt * 16 + g * 4);
            #pragma unroll
            for (int r = 0; r < 4; ++r)
                acc[dt][r] += ps * bf2f(vs[r]);
        }
        l += ps;
    }

    if (causal && NS == 1) {
        const float inv = 1.0f / l;
        short* orow = attn + (size_t)qg * DMODEL + qcol;
        #pragma unroll
        for (int dt = 0; dt < 4; ++dt)
            #pragma unroll
            for (int r = 0; r < 4; ++r)
                orow[dt * 16 + g * 4 + r] = f2bf(acc[dt][r] * inv);
    } else if (z == 0) {
        float* pml0 = causal ? pml0_c : pml0_q;
        const int stride = causal ? 2048 : 1024;
        const int base   = causal ? 1024 : SPOKES;
        short* orow = attn + (size_t)qg * DMODEL + qcol;
        #pragma unroll
        for (int dt = 0; dt < 4; ++dt)
            #pragma unroll
            for (int r = 0; r < 4; ++r)
                orow[dt * 16 + g * 4 + r] = f2bf(acc[dt][r]);
        if (g == 0) {
            float* p = pml0 + ((size_t)h * stride + (qg - base)) * 2;
            p[0] = Mlog;
            p[1] = l;
        }
    } else {
        const int slot = causal ? (qt < 32 ? qt - 16 : 16 + (qt - 32) * 2 + (z - 1))
                                : qb * 2 + (z - 1);
        short* pacc = causal ? pacc_c : pacc_q;
        float* pml  = causal ? pml_c  : pml_q;
        const int rl = w * 16 + c;            // row within 64-row block
        short* prow = pacc + ((size_t)slot * 64 + rl) * DMODEL + qcol;
        #pragma unroll
        for (int dt = 0; dt < 4; ++dt)
            #pragma unroll
            for (int r = 0; r < 4; ++r)
                prow[dt * 16 + g * 4 + r] = f2bf(acc[dt][r]);
        if (g == 0) {
            float* p = pml + ((size_t)(slot * 16 + h) * 64 + rl) * 2;
            p[0] = Mlog;
            p[1] = l;
        }
    }
}

// ---------------------------------------------------------------------------
// Merged combine (one launch; 64-row slots).
// ---------------------------------------------------------------------------
__global__ __launch_bounds__(256) void attn_combine_all(
    short* __restrict__ attn,
    const float* __restrict__ pml0_c, const short* __restrict__ pacc_c, const float* __restrict__ pml_c,
    const float* __restrict__ pml0_q, const short* __restrict__ pacc_q, const float* __restrict__ pml_q)
{
    const int gi = blockIdx.x * 256 + threadIdx.x;   // 3 x 131072 threads
    const int seg = gi >> 17;
    const int li  = gi & 131071;
    const int r = li >> 7;
    const int h = (li >> 3) & 15;
    const int o = li & 7;

    int rowbase, pml0_stride, pml0_off, slotBase, slotMul, nextra;
    const float* pml0; const short* pacc; const float* pml;
    if (seg == 0) {
        rowbase = 1024;   pml0_stride = 2048; pml0_off = 0;
        slotBase = 0;  slotMul = 1; nextra = 1;
        pml0 = pml0_c; pacc = pacc_c; pml = pml_c;
    } else if (seg == 1) {
        rowbase = 2048;   pml0_stride = 2048; pml0_off = 1024;
        slotBase = 16; slotMul = 2; nextra = 2;
        pml0 = pml0_c; pacc = pacc_c; pml = pml_c;
    } else {
        rowbase = SPOKES; pml0_stride = 1024; pml0_off = 0;
        slotBase = 0;  slotMul = 2; nextra = 2;
        pml0 = pml0_q; pacc = pacc_q; pml = pml_q;
    }

    const float* p0 = pml0 + ((size_t)h * pml0_stride + pml0_off + r) * 2;
    const float m0 = p0[0], l0 = p0[1];
    float M = m0;
    float me[2], le[2];
    for (int e = 0; e < nextra; ++e) {
        const int slot = slotBase + (r >> 6) * slotMul + e;
        const float* p = pml + ((size_t)(slot * 16 + h) * 64 + (r & 63)) * 2;
        me[e] = p[0]; le[e] = p[1];
        M = fmaxf(M, me[e]);
    }
    const float w0 = __expf(m0 - M);
    float L = w0 * l0;
    float we[2];
    for (int e = 0; e < nextra; ++e) { we[e] = __expf(me[e] - M); L += we[e] * le[e]; }

    short* arow = attn + (size_t)(rowbase + r) * DMODEL + h * 64 + o * 8;
    bf16x8 a0 = *(const bf16x8*)arow;
    float outv[8];
    #pragma unroll
    for (int j = 0; j < 8; ++j) outv[j] = w0 * bf2f(a0[j]);
    for (int e = 0; e < nextra; ++e) {
        const int slot = slotBase + (r >> 6) * slotMul + e;
        bf16x8 a = *(const bf16x8*)(pacc + ((size_t)slot * 64 + (r & 63)) * DMODEL + h * 64 + o * 8);
        #pragma unroll
        for (int j = 0; j < 8; ++j) outv[j] += we[e] * bf2f(a[j]);
    }
    const float inv = 1.0f / L;
    bf16x8 res;
    #pragma unroll
    for (int j = 0; j < 8; ++j) res[j] = f2bf(outv[j] * inv);
    *(bf16x8*)arow = res;
}

// ---------------------------------------------------------------------------
extern "C" void kernel_launch(void* const* d_in, const int* in_sizes, int n_in,
                              void* d_out, int out_size, void* d_ws, size_t ws_size,
                              hipStream_t stream)
{
    const float* x      = (const float*)d_in[0];
    const float* pos    = (const float*)d_in[1];
    const float* qkv_w  = (const float*)d_in[2];
    const float* out_w  = (const float*)d_in[3];
    const float* scale  = (const float*)d_in[4];
    const float* freqs  = (const float*)d_in[5];
    float*       out    = (float*)d_out;

    const size_t MB = 1024 * 1024;
    char* ws = (char*)d_ws;
    short* qkv_bf  = (short*)(ws);                       // [0,24MB)  qkv (live)
    short* x_bf    = (short*)(ws + 24 * MB);             // [24,32)   x -> attn (alias)
    short* wqkv_bf = (short*)(ws + 32 * MB);             // [32,38)   qkv_w -> query partials
    short* wout_bf = (short*)(ws + 38 * MB);             // [38,40)   out_w (live)
    short* pacc_c  = (short*)(ws + 40 * MB);             // [40,46)   48 slots x 64 x 1024 bf16 = 6MB
    float* pml_c   = (float*)(ws + 46 * MB);             // 393216 B  (48 slots x 16h x 64 x 2)
    float* pml0_c  = (float*)(ws + 46 * MB + 393216);    // 262144 B  (ends ~46.63MB)
    short* attn_bf = x_bf;                               // alias (x dead after gemm1)
    short* pacc_q  = wqkv_bf;                            // 32 slots x 64 x 1024 bf16 = 4MB
    float* pml_q   = (float*)((char*)wqkv_bf + 4194304); // 262144 B
    float* pml0_q  = (float*)((char*)wqkv_bf + 4456448); // 131072 B (ends ~36.4MB)

    const dim3 blk(256);

    // 0) single merged f32->bf16 conversion (x, qkv_w, out_w)
    cvt_all<<<dim3((CVT_N0 + CVT_N1 + CVT_N2) / 256), blk, 0, stream>>>(
        x, qkv_w, out_w, x_bf, wqkv_bf, wout_bf);

    // 1) qkv = x @ qkv_w^T with FUSED cos-scale + RoPE (+log2e on q) epilogue
    gemm_bf16<true, true><<<dim3(QKVN / 128, SEQL / 128), blk, 0, stream>>>(
        x_bf, wqkv_bf, qkv_bf, DMODEL, QKVN, pos, scale, freqs);

    // 2) fused attention (r13 best configuration)
    attn_fused<<<dim3(144, NH), blk, 0, stream>>>(
        qkv_bf, scale, attn_bf, pacc_c, pml_c, pml0_c, pacc_q, pml_q, pml0_q);

    // 3) single merged combine
    attn_combine_all<<<dim3(1536), blk, 0, stream>>>(
        attn_bf, pml0_c, pacc_c, pml_c, pml0_q, pacc_q, pml_q);

    // 4) out = attn @ out_w^T  (bf16 in, f32 out)
    gemm_bf16<false, false><<<dim3(DMODEL / 128, SEQL / 128), blk, 0, stream>>>(
        attn_bf, wout_bf, out, DMODEL, DMODEL, nullptr, nullptr, nullptr);
}